// Round 14
// baseline (193.178 us; speedup 1.0000x reference)
//
#include <hip/hip_runtime.h>
#include <math.h>

#define PI_D 3.14159265358979323846
#define PIF  3.14159265358979323846f
#define NLAT 128
#define NLON 256
#define LMAX 50
#define MMAX 50
#define NPTS 2048
#define NBT 16
#define NBA 32
#define NBIN (NBT * NBA)
#define WBIN 0.19634954084936207f   /* pi/16 */
#define INVW 5.092958178940651f     /* 16/pi */
#define BIG 1e30f
#define KMASK 0xFFFFF800u           /* high 21 bits of distance, low 11 = index */
#define MAGIC 0x1F2E3D4Cu           /* != 0xAAAAAAAA ws-poison */

__device__ __forceinline__ void insert3(float kf, float& k0, float& k1, float& k2) {
    float n1 = __builtin_amdgcn_fmed3f(kf, k0, k1);
    float n2 = __builtin_amdgcn_fmed3f(kf, k1, k2);
    k0 = fminf(kf, k0);
    k1 = n1;
    k2 = n2;
}

__device__ __forceinline__ float mkkey(float gt, float gl, float2 tl, int idx) {
    float dt = gt - tl.x, dl = gl - tl.y;
    float d = fmaf(dt, dt, dl * dl);
    return __uint_as_float((__float_as_uint(d) & KMASK) | (unsigned)idx);
}

// ---------------------------------------------------------------------------
// ONE dispatch, 256 blocks (= chip capacity, all co-resident), 1024 threads:
// Phase 1: blocks 0..127   = binned knn + interp + DFT, FOUR lat rows each.
//          blocks 128..255 = PCTW column k = bid-128, f32; block 128 zeroes
//          out[0].
// Join:    every block sets flags[bid]=MAGIC after a device-scope release
//          fence. Blocks 0..99 poll all 256 flags (device-scope atomic
//          reads; ws poison 0xAA != MAGIC so no reset needed), acquire-fence,
//          then run the Legendre contraction + loss for (b,l)=bid.
// ---------------------------------------------------------------------------
__global__ __launch_bounds__(1024) void mega_main(
    const float* __restrict__ pred, const float* __restrict__ tgt,
    float* __restrict__ pctwT, float* __restrict__ fre,
    unsigned* __restrict__ flags, float* __restrict__ out) {

    __shared__ float2 s_btl[NPTS];        // 16 KB
    __shared__ float  s_br[NPTS];         //  8 KB
    __shared__ int    s_cnt[NBIN];        //  2 KB
    __shared__ int    s_off[NBIN + 1];    //  2 KB
    __shared__ float  s_row[4][NLON];     //  4 KB
    __shared__ float  s_part[4][256];     //  4 KB

    int bid = blockIdx.x;
    int t = threadIdx.x;

    if (bid >= 128) {
        // ---------------- PCTW role, f32 (R13 verbatim, no early return) ----
        int k = bid - 128;                      // 0..127
        int m = t;
        if (k == 0 && m == 0) out[0] = 0.0f;    // init for phase-2 atomics
        if (m < MMAX) {
            double thd = PI_D * (double)k / 127.0;
            float cost = (float)cos(thd);
            float sint = (float)sin(thd);       // >= 0 on [0,pi]

            float c2 = (float)cos(2.0 * thd);
            float two_c2 = 2.0f * c2;
            float cp = 1.0f, cc = c2, v = 0.0f;
            for (int tt = 1; tt <= 63; ++tt) {
                v += 2.0f * cc / (float)(4 * tt * tt - 1);
                float cn = two_c2 * cc - cp;
                cp = cc;
                cc = cn;
            }
            float w = (2.0f / 127.0f) * (1.0f - v);
            if (k == 0 || k == 127) w *= 0.5f;

            float pmm = sqrtf(1.0f / (4.0f * PIF));
            for (int i = 1; i <= m; ++i)
                pmm = -pmm * sqrtf((2.0f * (float)i + 1.0f) / (2.0f * (float)i)) * sint;

            float* o = pctwT + (size_t)k * MMAX + m;   // pctwT[(l*NLAT+k)*MMAX+m]
            for (int l = 0; l < m; ++l) o[(size_t)l * NLAT * MMAX] = 0.0f;
            o[(size_t)m * NLAT * MMAX] = pmm * w;
            float plm2 = pmm, plm1 = 0.0f;
            if (m + 1 < LMAX) {
                plm1 = sqrtf(2.0f * (float)m + 3.0f) * cost * pmm;
                o[(size_t)(m + 1) * NLAT * MMAX] = plm1 * w;
            }
            for (int l = m + 2; l < LMAX; ++l) {
                float fl = (float)l;
                float denom = fl * fl - (float)(m * m);          // exact (<2^24)
                float a = sqrtf((4.0f * fl * fl - 1.0f) / denom);
                float b = sqrtf(((2.0f * fl + 1.0f) * (float)(l - 1 + m) * (float)(l - 1 - m)) /
                                ((2.0f * fl - 3.0f) * denom));
                float p = a * cost * plm1 - b * plm2;
                o[(size_t)l * NLAT * MMAX] = p * w;
                plm2 = plm1;
                plm1 = p;
            }
        }
    } else {
        // ---------------- KNN role (R13 verbatim) ----------------
        int f = bid >> 5;            // 0..3
        int lat0 = (bid & 31) * 4;   // first lat row of the quad
        const float* src = ((f < 2) ? pred : tgt) + (size_t)(f & 1) * NPTS * 3;

        if (t < NBIN) s_cnt[t] = 0;
        __syncthreads();

        float pth[2], paz[2], pr[2];
        int pbin[2];
#pragma unroll
        for (int i = 0; i < 2; ++i) {
            int n = t + 1024 * i;
            float x = src[3 * n], y = src[3 * n + 1], z = src[3 * n + 2];
            float s1 = z * z;
            float s2 = s1 + y * y;
            float s3 = s2 + x * x;
            float r = sqrtf(s3);
            float rho = sqrtf(s2);
            float th = acosf(x / r);
            float a = acosf(y / rho);
            float az = (z < 0.0f) ? (a + (2.0f * PIF - 2.0f * a)) : a;
            az -= PIF;
            int bt = min(max((int)(th * INVW), 0), NBT - 1);
            int ba = min(max((int)((az + PIF) * INVW), 0), NBA - 1);
            int b = bt * NBA + ba;
            pth[i] = th; paz[i] = az; pr[i] = r; pbin[i] = b;
            atomicAdd(&s_cnt[b], 1);
        }
        __syncthreads();

        if (t == 0) s_off[NBIN] = NPTS;
        if (t < 64) {
            int base = t * 8;
            int loc[8];
            int run = 0;
#pragma unroll
            for (int i = 0; i < 8; ++i) { loc[i] = run; run += s_cnt[base + i]; }
            int x = run;
#pragma unroll
            for (int d = 1; d < 64; d <<= 1) {
                int y = __shfl_up(x, d);
                if (t >= d) x += y;
            }
            int ex = x - run;
#pragma unroll
            for (int i = 0; i < 8; ++i) s_off[base + i] = ex + loc[i];
        }
        __syncthreads();
        if (t < NBIN) s_cnt[t] = s_off[t];
        __syncthreads();
#pragma unroll
        for (int i = 0; i < 2; ++i) {
            int pos = atomicAdd(&s_cnt[pbin[i]], 1);
            s_btl[pos] = make_float2(pth[i], paz[i]);
            s_br[pos] = pr[i];
        }
        __syncthreads();

        int rl = t >> 8;            // 0..3, wave-uniform
        int j = t & 255;            // lon
        int lat = lat0 + rl;
        float gt = (float)((double)lat * PI_D / 128.0);
        float gl = (float)(((double)j - 128.0) * PI_D / 128.0);
        float glp = gl + PIF;
        int bt0 = lat >> 3;
        int ba0 = j >> 3;

        auto scan_seg = [&](int i, int i1, float& q0, float& q1, float& q2) {
            for (; i + 4 <= i1; i += 4) {
                float2 a0 = s_btl[i];
                float2 a1 = s_btl[i + 1];
                float2 a2 = s_btl[i + 2];
                float2 a3 = s_btl[i + 3];
                insert3(mkkey(gt, gl, a0, i), q0, q1, q2);
                insert3(mkkey(gt, gl, a1, i + 1), q0, q1, q2);
                insert3(mkkey(gt, gl, a2, i + 2), q0, q1, q2);
                insert3(mkkey(gt, gl, a3, i + 3), q0, q1, q2);
            }
            for (; i < i1; ++i)
                insert3(mkkey(gt, gl, s_btl[i], i), q0, q1, q2);
        };

        float k0 = BIG, k1 = BIG, k2 = BIG;
        {
            int rtl = max(bt0 - 1, 0), rth = min(bt0 + 1, NBT - 1);
            int bal = max(ba0 - 1, 0), bah = min(ba0 + 1, NBA - 1);
            for (int bt = rtl; bt <= rth; ++bt)
                scan_seg(s_off[bt * NBA + bal], s_off[bt * NBA + bah + 1], k0, k1, k2);
        }

        bool done;
        {
            float safe = BIG;
            if (bt0 - 1 > 0)       safe = fminf(safe, gt - (float)(bt0 - 1) * WBIN);
            if (bt0 + 1 < NBT - 1) safe = fminf(safe, (float)(bt0 + 2) * WBIN - gt);
            if (ba0 - 1 > 0)       safe = fminf(safe, glp - (float)(ba0 - 1) * WBIN);
            if (ba0 + 1 < NBA - 1) safe = fminf(safe, (float)(ba0 + 2) * WBIN - glp);
            done = (k2 <= safe * safe);
        }

        for (int R = 2; R <= 31; ++R) {
            if (__all(done)) break;
            if (!done) {
                int btl = bt0 - R, bth = bt0 + R;
                int lo = max(btl, 0), hi = min(bth, NBT - 1);
                int bal = max(ba0 - R, 0), bah = min(ba0 + R, NBA - 1);
                for (int bt = lo; bt <= hi; ++bt) {
                    if (bt == btl || bt == bth) {
                        scan_seg(s_off[bt * NBA + bal], s_off[bt * NBA + bah + 1], k0, k1, k2);
                    } else {
                        if (ba0 - R >= 0) {
                            int b = bt * NBA + ba0 - R;
                            scan_seg(s_off[b], s_off[b + 1], k0, k1, k2);
                        }
                        if (ba0 + R <= NBA - 1) {
                            int b = bt * NBA + ba0 + R;
                            scan_seg(s_off[b], s_off[b + 1], k0, k1, k2);
                        }
                    }
                }
                float safe = BIG;
                if (bt0 - R > 0)       safe = fminf(safe, gt - (float)(bt0 - R) * WBIN);
                if (bt0 + R < NBT - 1) safe = fminf(safe, (float)(bt0 + R + 1) * WBIN - gt);
                if (ba0 - R > 0)       safe = fminf(safe, glp - (float)(ba0 - R) * WBIN);
                if (ba0 + R < NBA - 1) safe = fminf(safe, (float)(ba0 + R + 1) * WBIN - glp);
                if (k2 <= safe * safe) done = true;
            }
        }

        {
            int i0 = __float_as_uint(k0) & 0x7FF;
            int i1 = __float_as_uint(k1) & 0x7FF;
            int i2 = __float_as_uint(k2) & 0x7FF;
            float2 p0 = s_btl[i0];
            float2 p1 = s_btl[i1];
            float2 p2 = s_btl[i2];
            float dt0 = gt - p0.x, dl0 = gl - p0.y;
            float dt1 = gt - p1.x, dl1 = gl - p1.y;
            float dt2 = gt - p2.x, dl2 = gl - p2.y;
            float d0 = fmaf(dt0, dt0, dl0 * dl0);
            float d1 = fmaf(dt1, dt1, dl1 * dl1);
            float d2 = fmaf(dt2, dt2, dl2 * dl2);
            float s = d0 + d1 + d2;
            s_row[rl][j] = (d0 * s_br[i0] + d1 * s_br[i1] + d2 * s_br[i2]) / s;
        }
        __syncthreads();

        {
            int q = (t >> 6) & 3;
            int mm = t & 63;
            if (mm < MMAX) {
                int bs = q * 64;
                const float W0 = 2.0f * PIF / 256.0f;
                float cphi2 = 2.0f * __cosf(W0 * (float)mm);
                float acc = 0.0f;
#pragma unroll
                for (int seg = 0; seg < 4; ++seg) {
                    int i0 = bs + seg * 16;
                    float c0 = __cosf(W0 * (float)((i0 * mm) & 255));
                    float c1 = __cosf(W0 * (float)(((i0 + 1) * mm) & 255));
                    acc = fmaf(s_row[rl][i0], c0, acc);
                    acc = fmaf(s_row[rl][i0 + 1], c1, acc);
#pragma unroll
                    for (int i = 2; i < 16; ++i) {
                        float cn = fmaf(cphi2, c1, -c0);
                        acc = fmaf(s_row[rl][i0 + i], cn, acc);
                        c0 = c1;
                        c1 = cn;
                    }
                }
                s_part[rl][q * 64 + mm] = acc;
            }
        }
        __syncthreads();
        {
            int mm = t & 255;
            if (mm < MMAX) {
                const float* pp = s_part[rl];
                float v = ((pp[mm] + pp[64 + mm]) + (pp[128 + mm] + pp[192 + mm])) *
                          (float)(2.0 * PI_D / (double)NLON);
                fre[(f * NLAT + lat0 + rl) * MMAX + mm] = v;
            }
        }
    }

    // ---------------- join: device-scope release + flag ----------------
    __syncthreads();
    __threadfence();
    if (t == 0) atomicExch(&flags[bid], MAGIC);

    if (bid >= 2 * LMAX) return;

    // wait for all 256 flags (bounded: assumption failure -> wrong answer,
    // caught by validation, never a hang)
    {
        bool alldone = false;
        for (int it = 0; it < 200000 && !alldone; ++it) {
            int ok = 1;
            if (t < 256) ok = (atomicAdd(&flags[t], 0u) == MAGIC) ? 1 : 0;
            alldone = (__syncthreads_count(ok) == 1024);
        }
    }
    __threadfence();   // acquire: see remote fre/pctwT/out writes

    // ---------------- Phase 2: contraction + loss (blocks 0..99) ----------
    {
        int b = bid / LMAX;
        int l = bid % LMAX;
        int mm = t & 63;
        int kq = (t >> 6) & 3;
        float* spp = &s_row[0][0];       // overlay: 256 floats
        float* stt = &s_row[2][0];       // overlay: 256 floats
        float pc = 0.0f, tc = 0.0f;
        if (t < 256 && mm < MMAX) {
            const float* pw = pctwT + ((size_t)l * NLAT + kq * 32) * MMAX + mm;
            const float* fp = fre + ((size_t)b * NLAT + kq * 32) * MMAX + mm;
            const float* ft = fre + ((size_t)(2 + b) * NLAT + kq * 32) * MMAX + mm;
#pragma unroll 8
            for (int k = 0; k < 32; ++k) {
                float w = pw[k * MMAX];
                pc += fp[k * MMAX] * w;
                tc += ft[k * MMAX] * w;
            }
        }
        if (t < 256) {
            spp[kq * 64 + mm] = pc;
            stt[kq * 64 + mm] = tc;
        }
        __syncthreads();
        if (t < 64) {
            int m2 = t;
            float pcs = (spp[m2] + spp[64 + m2]) + (spp[128 + m2] + spp[192 + m2]);
            float tcs = (stt[m2] + stt[64 + m2]) + (stt[128 + m2] + stt[192 + m2]);
            float diff = pcs - tcs;
            double dl_ = (double)(49 - l);
            float rw = (float)exp(-(dl_ * dl_) / 5000.0);
            float contrib = (m2 < MMAX) ? diff * diff * rw * 0.5f : 0.0f;
            for (int off = 32; off > 0; off >>= 1) contrib += __shfl_down(contrib, off);
            if (m2 == 0) atomicAdd(out, contrib);
        }
    }
}

// ---------------------------------------------------------------------------
extern "C" void kernel_launch(void* const* d_in, const int* in_sizes, int n_in,
                              void* d_out, int out_size, void* d_ws, size_t ws_size,
                              hipStream_t stream) {
    const float* pred = (const float*)d_in[0];
    const float* tgt = (const float*)d_in[1];
    float* ws = (float*)d_ws;

    float*    pctwT = ws;             // 50*128*50 = 320000 floats
    float*    fre   = ws + 320000;    // 4*128*50  =  25600 floats
    unsigned* flags = (unsigned*)(ws + 345600);  // 256 words (poisoned 0xAA)
    float* out = (float*)d_out;

    mega_main<<<256, 1024, 0, stream>>>(pred, tgt, pctwT, fre, flags, out);
}

// Round 15
// 78.221 us; speedup vs baseline: 2.4696x; 2.4696x over previous
//
#include <hip/hip_runtime.h>
#include <math.h>

#define PI_D 3.14159265358979323846
#define PIF  3.14159265358979323846f
#define NLAT 128
#define NLON 256
#define LMAX 50
#define MMAX 50
#define NPTS 2048
#define NBT 16
#define NBA 32
#define NBIN (NBT * NBA)
#define WBIN 0.19634954084936207f   /* pi/16 */
#define INVW 5.092958178940651f     /* 16/pi */
#define BIG 1e30f
#define KMASK 0xFFFFF800u           /* high 21 bits of distance, low 11 = index */

__device__ __forceinline__ void insert3(float kf, float& k0, float& k1, float& k2) {
    float n1 = __builtin_amdgcn_fmed3f(kf, k0, k1);
    float n2 = __builtin_amdgcn_fmed3f(kf, k1, k2);
    k0 = fminf(kf, k0);
    k1 = n1;
    k2 = n2;
}

__device__ __forceinline__ float mkkey(float gt, float gl, float2 tl, int idx) {
    float dt = gt - tl.x, dl = gl - tl.y;
    float d = fmaf(dt, dt, dl * dl);
    return __uint_as_float((__float_as_uint(d) & KMASK) | (unsigned)idx);
}

// ---------------------------------------------------------------------------
// Kernel 1 (fused), 256 blocks = 1 per CU, 1024 threads:
//   blocks 0..127   = binned knn + interp + DFT for FOUR lat rows (one field,
//                     lat-quad). Each thread: one (lon,lat) query + one DFT task.
//   blocks 128..255 = PCTW column k = bid-128, f32 (lane = m);
//                     block 128 zeroes out[0].
// ---------------------------------------------------------------------------
__global__ __launch_bounds__(1024) void fused_main(
    const float* __restrict__ pred, const float* __restrict__ tgt,
    float* __restrict__ pctwT, float* __restrict__ fre, float* __restrict__ out) {

    __shared__ float2 s_btl[NPTS];        // (theta, az) in bin order   16 KB
    __shared__ float  s_br[NPTS];         // radius in bin order         8 KB
    __shared__ int    s_cnt[NBIN];        // counts, then scatter cursor 2 KB
    __shared__ int    s_off[NBIN + 1];    // bin start offsets           2 KB
    __shared__ float  s_row[4][NLON];     // interp rows                 4 KB
    __shared__ float  s_part[4][256];     // DFT partials                4 KB

    int bid = blockIdx.x;
    int t = threadIdx.x;

    if (bid >= 128) {
        // ---------------- PCTW role, f32 (R10-validated) ----------------
        int k = bid - 128;                      // 0..127
        int m = t;
        if (k == 0 && m == 0) out[0] = 0.0f;    // init for contract's atomics
        if (m >= MMAX) return;

        double thd = PI_D * (double)k / 127.0;
        float cost = (float)cos(thd);
        float sint = (float)sin(thd);           // >= 0 on [0,pi]

        // Clenshaw-Curtis weight (Nn=127, odd), f32 Chebyshev recurrence
        float c2 = (float)cos(2.0 * thd);
        float two_c2 = 2.0f * c2;
        float cp = 1.0f, cc = c2, v = 0.0f;
        for (int tt = 1; tt <= 63; ++tt) {
            v += 2.0f * cc / (float)(4 * tt * tt - 1);
            float cn = two_c2 * cc - cp;
            cp = cc;
            cc = cn;
        }
        float w = (2.0f / 127.0f) * (1.0f - v);
        if (k == 0 || k == 127) w *= 0.5f;

        float pmm = sqrtf(1.0f / (4.0f * PIF));
        for (int i = 1; i <= m; ++i)
            pmm = -pmm * sqrtf((2.0f * (float)i + 1.0f) / (2.0f * (float)i)) * sint;

        float* o = pctwT + (size_t)k * MMAX + m;   // pctwT[(l*NLAT+k)*MMAX+m]
        for (int l = 0; l < m; ++l) o[(size_t)l * NLAT * MMAX] = 0.0f;
        o[(size_t)m * NLAT * MMAX] = pmm * w;
        float plm2 = pmm, plm1 = 0.0f;
        if (m + 1 < LMAX) {
            plm1 = sqrtf(2.0f * (float)m + 3.0f) * cost * pmm;
            o[(size_t)(m + 1) * NLAT * MMAX] = plm1 * w;
        }
        for (int l = m + 2; l < LMAX; ++l) {
            float fl = (float)l;
            float denom = fl * fl - (float)(m * m);          // exact (<2^24)
            float a = sqrtf((4.0f * fl * fl - 1.0f) / denom);
            float b = sqrtf(((2.0f * fl + 1.0f) * (float)(l - 1 + m) * (float)(l - 1 - m)) /
                            ((2.0f * fl - 3.0f) * denom));
            float p = a * cost * plm1 - b * plm2;
            o[(size_t)l * NLAT * MMAX] = p * w;
            plm2 = plm1;
            plm1 = p;
        }
        return;
    }

    // ---------------- KNN role: bin once, query FOUR lat rows ----------------
    int f = bid >> 5;            // 0..3
    int lat0 = (bid & 31) * 4;   // first lat row of the quad
    const float* src = ((f < 2) ? pred : tgt) + (size_t)(f & 1) * NPTS * 3;

    if (t < NBIN) s_cnt[t] = 0;
    __syncthreads();

    // to_spherical into registers (exact reference fp order) + bin counts
    float pth[2], paz[2], pr[2];
    int pbin[2];
#pragma unroll
    for (int i = 0; i < 2; ++i) {
        int n = t + 1024 * i;
        float x = src[3 * n], y = src[3 * n + 1], z = src[3 * n + 2];
        float s1 = z * z;
        float s2 = s1 + y * y;
        float s3 = s2 + x * x;
        float r = sqrtf(s3);
        float rho = sqrtf(s2);
        float th = acosf(x / r);
        float a = acosf(y / rho);
        float az = (z < 0.0f) ? (a + (2.0f * PIF - 2.0f * a)) : a;
        az -= PIF;
        int bt = min(max((int)(th * INVW), 0), NBT - 1);
        int ba = min(max((int)((az + PIF) * INVW), 0), NBA - 1);
        int b = bt * NBA + ba;
        pth[i] = th; paz[i] = az; pr[i] = r; pbin[i] = b;
        atomicAdd(&s_cnt[b], 1);
    }
    __syncthreads();

    // exclusive scan of 512 counts by one wave (8 bins per lane)
    if (t == 0) s_off[NBIN] = NPTS;
    if (t < 64) {
        int base = t * 8;
        int loc[8];
        int run = 0;
#pragma unroll
        for (int i = 0; i < 8; ++i) { loc[i] = run; run += s_cnt[base + i]; }
        int x = run;
#pragma unroll
        for (int d = 1; d < 64; d <<= 1) {
            int y = __shfl_up(x, d);
            if (t >= d) x += y;
        }
        int ex = x - run;
#pragma unroll
        for (int i = 0; i < 8; ++i) s_off[base + i] = ex + loc[i];
    }
    __syncthreads();
    if (t < NBIN) s_cnt[t] = s_off[t];
    __syncthreads();
#pragma unroll
    for (int i = 0; i < 2; ++i) {
        int pos = atomicAdd(&s_cnt[pbin[i]], 1);
        s_btl[pos] = make_float2(pth[i], paz[i]);
        s_br[pos] = pr[i];
    }
    __syncthreads();

    // ---- 3-NN query: one (lon, lat) per thread; rl is wave-uniform ----
    int rl = t >> 8;            // 0..3, uniform within a wave
    int j = t & 255;            // lon
    int lat = lat0 + rl;
    float gt = (float)((double)lat * PI_D / 128.0);
    float gl = (float)(((double)j - 128.0) * PI_D / 128.0);
    float glp = gl + PIF;
    int bt0 = lat >> 3;         // wave-uniform
    int ba0 = j >> 3;

    auto scan_seg = [&](int i, int i1, float& q0, float& q1, float& q2) {
        for (; i + 4 <= i1; i += 4) {
            float2 a0 = s_btl[i];
            float2 a1 = s_btl[i + 1];
            float2 a2 = s_btl[i + 2];
            float2 a3 = s_btl[i + 3];
            insert3(mkkey(gt, gl, a0, i), q0, q1, q2);
            insert3(mkkey(gt, gl, a1, i + 1), q0, q1, q2);
            insert3(mkkey(gt, gl, a2, i + 2), q0, q1, q2);
            insert3(mkkey(gt, gl, a3, i + 3), q0, q1, q2);
        }
        for (; i < i1; ++i)
            insert3(mkkey(gt, gl, s_btl[i], i), q0, q1, q2);
    };

    float k0 = BIG, k1 = BIG, k2 = BIG;
    {
        int rtl = max(bt0 - 1, 0), rth = min(bt0 + 1, NBT - 1);
        int bal = max(ba0 - 1, 0), bah = min(ba0 + 1, NBA - 1);
        for (int bt = rtl; bt <= rth; ++bt)
            scan_seg(s_off[bt * NBA + bal], s_off[bt * NBA + bah + 1], k0, k1, k2);
    }

    bool done;
    {
        float safe = BIG;
        if (bt0 - 1 > 0)       safe = fminf(safe, gt - (float)(bt0 - 1) * WBIN);
        if (bt0 + 1 < NBT - 1) safe = fminf(safe, (float)(bt0 + 2) * WBIN - gt);
        if (ba0 - 1 > 0)       safe = fminf(safe, glp - (float)(ba0 - 1) * WBIN);
        if (ba0 + 1 < NBA - 1) safe = fminf(safe, (float)(ba0 + 2) * WBIN - glp);
        done = (k2 <= safe * safe);
    }

    // fallback: expanding rings R>=2 (R6/R12 verbatim)
    for (int R = 2; R <= 31; ++R) {
        if (__all(done)) break;
        if (!done) {
            int btl = bt0 - R, bth = bt0 + R;
            int lo = max(btl, 0), hi = min(bth, NBT - 1);
            int bal = max(ba0 - R, 0), bah = min(ba0 + R, NBA - 1);
            for (int bt = lo; bt <= hi; ++bt) {
                if (bt == btl || bt == bth) {
                    scan_seg(s_off[bt * NBA + bal], s_off[bt * NBA + bah + 1], k0, k1, k2);
                } else {
                    if (ba0 - R >= 0) {
                        int b = bt * NBA + ba0 - R;
                        scan_seg(s_off[b], s_off[b + 1], k0, k1, k2);
                    }
                    if (ba0 + R <= NBA - 1) {
                        int b = bt * NBA + ba0 + R;
                        scan_seg(s_off[b], s_off[b + 1], k0, k1, k2);
                    }
                }
            }
            float safe = BIG;
            if (bt0 - R > 0)       safe = fminf(safe, gt - (float)(bt0 - R) * WBIN);
            if (bt0 + R < NBT - 1) safe = fminf(safe, (float)(bt0 + R + 1) * WBIN - gt);
            if (ba0 - R > 0)       safe = fminf(safe, glp - (float)(ba0 - R) * WBIN);
            if (ba0 + R < NBA - 1) safe = fminf(safe, (float)(ba0 + R + 1) * WBIN - glp);
            if (k2 <= safe * safe) done = true;
        }
    }

    // epilogue: indices from keys, exact distances, interp weights
    {
        int i0 = __float_as_uint(k0) & 0x7FF;
        int i1 = __float_as_uint(k1) & 0x7FF;
        int i2 = __float_as_uint(k2) & 0x7FF;
        float2 p0 = s_btl[i0];
        float2 p1 = s_btl[i1];
        float2 p2 = s_btl[i2];
        float dt0 = gt - p0.x, dl0 = gl - p0.y;
        float dt1 = gt - p1.x, dl1 = gl - p1.y;
        float dt2 = gt - p2.x, dl2 = gl - p2.y;
        float d0 = fmaf(dt0, dt0, dl0 * dl0);
        float d1 = fmaf(dt1, dt1, dl1 * dl1);
        float d2 = fmaf(dt2, dt2, dl2 * dl2);
        float s = d0 + d1 + d2;
        s_row[rl][j] = (d0 * s_br[i0] + d1 * s_br[i1] + d2 * s_br[i2]) / s;
    }
    __syncthreads();

    // DFT: one (row, quarter, mode) task per thread. Row reads wave-uniform
    // broadcasts; cosines via Chebyshev recurrence re-seeded every 16 steps
    // (exact integer-mod angle reduction) -- zero LDS gathers.
    {
        int q = (t >> 6) & 3;  // quarter
        int mm = t & 63;       // mode
        if (mm < MMAX) {
            int bs = q * 64;
            const float W0 = 2.0f * PIF / 256.0f;
            float cphi2 = 2.0f * __cosf(W0 * (float)mm);
            float acc = 0.0f;
#pragma unroll
            for (int seg = 0; seg < 4; ++seg) {
                int i0 = bs + seg * 16;
                float c0 = __cosf(W0 * (float)((i0 * mm) & 255));
                float c1 = __cosf(W0 * (float)(((i0 + 1) * mm) & 255));
                acc = fmaf(s_row[rl][i0], c0, acc);
                acc = fmaf(s_row[rl][i0 + 1], c1, acc);
#pragma unroll
                for (int i = 2; i < 16; ++i) {
                    float cn = fmaf(cphi2, c1, -c0);
                    acc = fmaf(s_row[rl][i0 + i], cn, acc);
                    c0 = c1;
                    c1 = cn;
                }
            }
            s_part[rl][q * 64 + mm] = acc;
        }
    }
    __syncthreads();
    {
        int mm = t & 255;
        if (mm < MMAX) {
            const float* pp = s_part[rl];
            float v = ((pp[mm] + pp[64 + mm]) + (pp[128 + mm] + pp[192 + mm])) *
                      (float)(2.0 * PI_D / (double)NLON);
            fre[(f * NLAT + lat0 + rl) * MMAX + mm] = v;
        }
    }
}

// ---------------------------------------------------------------------------
// Kernel 2: Legendre contraction + loss (R10 verbatim). Block per (b,l);
// 256 threads = (mm 0..63) x (k-quarter 0..3); LDS reduce; one atomic/block.
// ---------------------------------------------------------------------------
__global__ __launch_bounds__(256) void contract_loss(const float* __restrict__ fre,
                                                     const float* __restrict__ pctwT,
                                                     float* __restrict__ out) {
    int b = blockIdx.x / LMAX;
    int l = blockIdx.x % LMAX;
    int mm = threadIdx.x & 63;
    int kq = threadIdx.x >> 6;
    __shared__ float sp[4][64], st_[4][64];
    float pc = 0.0f, tc = 0.0f;
    if (mm < MMAX) {
        const float* pw = pctwT + ((size_t)l * NLAT + kq * 32) * MMAX + mm;
        const float* fp = fre + ((size_t)b * NLAT + kq * 32) * MMAX + mm;
        const float* ft = fre + ((size_t)(2 + b) * NLAT + kq * 32) * MMAX + mm;
#pragma unroll 8
        for (int k = 0; k < 32; ++k) {
            float w = pw[k * MMAX];
            pc += fp[k * MMAX] * w;
            tc += ft[k * MMAX] * w;
        }
    }
    sp[kq][mm] = pc;
    st_[kq][mm] = tc;
    __syncthreads();
    if (threadIdx.x < 64) {
        int m2 = threadIdx.x;
        float pcs = (sp[0][m2] + sp[1][m2]) + (sp[2][m2] + sp[3][m2]);
        float tcs = (st_[0][m2] + st_[1][m2]) + (st_[2][m2] + st_[3][m2]);
        float diff = pcs - tcs;
        double dl_ = (double)(49 - l);
        float rw = (float)exp(-(dl_ * dl_) / 5000.0);
        float contrib = (m2 < MMAX) ? diff * diff * rw * 0.5f : 0.0f;
        for (int off = 32; off > 0; off >>= 1) contrib += __shfl_down(contrib, off);
        if (m2 == 0) atomicAdd(out, contrib);
    }
}

// ---------------------------------------------------------------------------
extern "C" void kernel_launch(void* const* d_in, const int* in_sizes, int n_in,
                              void* d_out, int out_size, void* d_ws, size_t ws_size,
                              hipStream_t stream) {
    const float* pred = (const float*)d_in[0];
    const float* tgt = (const float*)d_in[1];
    float* ws = (float*)d_ws;

    float* pctwT = ws;            // 50*128*50 = 320000 floats
    float* fre   = ws + 320000;   // 4*128*50  =  25600 floats
    float* out = (float*)d_out;

    fused_main<<<256, 1024, 0, stream>>>(pred, tgt, pctwT, fre, out);
    contract_loss<<<2 * LMAX, 256, 0, stream>>>(fre, pctwT, out);
}